// Round 2
// baseline (496.394 us; speedup 1.0000x reference)
//
#include <hip/hip_runtime.h>
#include <hip/hip_bf16.h>
#include <hip/hip_fp16.h>

// Problem dims
#define SEQ   2048
#define BATCH 16
#define DIN   512
#define HID   512
#define MROWS (SEQ*BATCH)   // 32768 GEMM rows (s,b)
#define KDIM  DIN           // 512

// Chunking: one 128-row m-tile = 8 timesteps x 16 batches = one scan chunk
#define NCH  256            // chunks along S (SEQ/8)
#define NSEQ (2*BATCH*HID)  // 16384 independent recurrences

typedef unsigned short u16;
typedef __bf16 bf16x8 __attribute__((ext_vector_type(8)));
typedef float  f32x4  __attribute__((ext_vector_type(4)));

__device__ __forceinline__ u16 f2bf(float x) {
  unsigned u = __float_as_uint(x);
  unsigned r = (u + 0x7fffu + ((u >> 16) & 1u)) >> 16;   // RNE
  return (u16)r;
}

__device__ __forceinline__ unsigned pkh(float a, float b) {
  __half2 h = __floats2half2_rn(a, b);
  return *(const unsigned*)&h;
}
__device__ __forceinline__ float2 uph(unsigned x) {
  __half2 h = *(const __half2*)&x;
  return __half22float2(h);
}

__device__ __forceinline__ void async_ld16(const void* g, void* l) {
  __builtin_amdgcn_global_load_lds(
      (const __attribute__((address_space(1))) void*)g,
      (__attribute__((address_space(3))) void*)l, 16, 0, 0);
}

__device__ __forceinline__ float sig_fast(float x) {
  return __builtin_amdgcn_rcpf(1.f + __expf(-x));
}
__device__ __forceinline__ float tanh_fast(float x) {
  return 1.f - 2.f * __builtin_amdgcn_rcpf(1.f + __expf(2.f * x));
}

// ---- fp32 -> bf16 conversion (vectorized, 4 elems/thread) ----
__global__ void cvt_kernel(const float* __restrict__ in, u16* __restrict__ out, int n4) {
  int i = blockIdx.x * blockDim.x + threadIdx.x;
  if (i >= n4) return;
  const float4 v = ((const float4*)in)[i];
  uint2 r;
  r.x = (unsigned)f2bf(v.x) | ((unsigned)f2bf(v.y) << 16);
  r.y = (unsigned)f2bf(v.z) | ((unsigned)f2bf(v.w) << 16);
  ((uint2*)out)[i] = r;
}

// ---- Fused GEMM + bias + activation + intra-chunk scan epilogue ----
// Block: 128 m-rows (8 s x 16 b) x 192 n-cols = all 3 gates for a 64-h tile of
// one direction.  n_local = p*96 + gate*32 + hs  ->  W row = gate*512 + hb + p*32 + hs.
// Wave (4 waves, 2m x 2p): 64 m x 96 n; frag ni: gate = ni>>1, h-sub = (ni&1)*16.
// Epilogue: per lane (b = lane&15) scan 4 in-lane steps (mi) + cross-wave LDS
// exchange -> per-step prefixes (H,P); writes u = o*H, v = o*P (fp16, dir-sliced)
// and the per-chunk (A=P_last, C=H_last) summary (fp32).
__launch_bounds__(256)
__global__ void gemm_fused(const u16* __restrict__ A, const u16* __restrict__ B,
                           const float* __restrict__ bfw, const float* __restrict__ bbw,
                           u16* __restrict__ U, u16* __restrict__ V,
                           float* __restrict__ ACn)
{
  __shared__ __align__(16) u16 sA[128 * 64];   // 16 KB
  __shared__ __align__(16) u16 sB[192 * 64];   // 24 KB

  const int t    = threadIdx.x;
  const int wave = t >> 6;
  const int lane = t & 63;
  const int m0  = blockIdx.y * 128;
  const int dir = blockIdx.x >> 3;
  const int hb  = (blockIdx.x & 7) * 64;
  const int wm  = (wave >> 1) * 64;   // m half
  const int p   = wave & 1;           // n half (h-sub-tile of 32)
  const int wn  = p * 96;

  f32x4 acc[4][6] = {};

  // staging: lane -> (rloc = lane>>3, c = lane&7); global 16B chunk g = c ^ rloc
  const int rloc = lane >> 3;
  const int gch  = (lane & 7) ^ rloc;
  const u16* gA  = A + (size_t)(m0 + wave * 32 + rloc) * KDIM + gch * 8;
  const u16* WbD = B + (size_t)dir * (3 * HID * KDIM);
  unsigned gBo[6];
#pragma unroll
  for (int j = 0; j < 6; j++) {
    const int nl = wave * 48 + j * 8 + rloc;      // 0..191
    const int pp = nl >= 96 ? 1 : 0;
    const int r  = nl - pp * 96;
    const int wrow = (r >> 5) * HID + hb + pp * 32 + (r & 31);
    gBo[j] = (unsigned)(wrow * KDIM + gch * 8);
  }

  const int lm = lane & 15;            // fragment index (= batch b for A rows)
  const int q  = lane >> 4;            // k-quad / n-reg group
  const int xs = lm & 7;               // read-side swizzle = row&7

  for (int kt = 0; kt < KDIM; kt += 64) {
    __syncthreads();
#pragma unroll
    for (int j = 0; j < 4; j++)
      async_ld16(gA + kt + (size_t)(j * 8) * KDIM, sA + (wave * 32 + j * 8) * 64);
#pragma unroll
    for (int j = 0; j < 6; j++)
      async_ld16(WbD + gBo[j] + kt, sB + (wave * 48 + j * 8) * 64);
    __syncthreads();

#pragma unroll
    for (int s = 0; s < 2; s++) {
      const int cofs = ((s * 4 + q) ^ xs) * 8;
      bf16x8 af[4], bfr[6];
#pragma unroll
      for (int mi = 0; mi < 4; mi++)
        af[mi] = *(const bf16x8*)(sA + (wm + mi * 16 + lm) * 64 + cofs);
#pragma unroll
      for (int ni = 0; ni < 6; ni++)
        bfr[ni] = *(const bf16x8*)(sB + (wn + ni * 16 + lm) * 64 + cofs);
#pragma unroll
      for (int mi = 0; mi < 4; mi++)
#pragma unroll
        for (int ni = 0; ni < 6; ni++)  // swapped: D col=lane&15 (m), row=q*4+i (n)
          acc[mi][ni] = __builtin_amdgcn_mfma_f32_16x16x32_bf16(bfr[ni], af[mi], acc[mi][ni], 0, 0, 0);
    }
  }

  // ---- epilogue ----
  // lane holds: m = m0 + wm + mi*16 + lm  (b = lm, s_local = (wave>>1)*4 + mi)
  //             h = hb + p*32 + (ni&1)*16 + q*4 + e, gate = ni>>1
  const float* bias = dir ? bbw : bfw;
  const int hcol0 = hb + p * 32 + q * 4;

  f32x4 bz[2], bff[2], bo[2];
#pragma unroll
  for (int j = 0; j < 2; j++) {
    float4 t0 = *(const float4*)(bias + 0 * HID + hcol0 + j * 16);
    float4 t1 = *(const float4*)(bias + 1 * HID + hcol0 + j * 16);
    float4 t2 = *(const float4*)(bias + 2 * HID + hcol0 + j * 16);
    bz[j][0] = t0.x; bz[j][1] = t0.y; bz[j][2] = t0.z; bz[j][3] = t0.w;
    bff[j][0] = t1.x; bff[j][1] = t1.y; bff[j][2] = t1.z; bff[j][3] = t1.w;
    bo[j][0] = t2.x; bo[j][1] = t2.y; bo[j][2] = t2.z; bo[j][3] = t2.w;
  }

  // activations in place: acc[mi][0+j] = c = f*z ; acc[mi][2+j] = a = 1-f ; acc[mi][4+j] = o
#pragma unroll
  for (int mi = 0; mi < 4; mi++)
#pragma unroll
    for (int j = 0; j < 2; j++)
#pragma unroll
      for (int e = 0; e < 4; e++) {
        const float z = tanh_fast(acc[mi][j][e] + bz[j][e]);
        const float f = sig_fast(acc[mi][2 + j][e] + bff[j][e]);
        const float o = sig_fast(acc[mi][4 + j][e] + bo[j][e]);
        acc[mi][j][e]     = f * z;
        acc[mi][2 + j][e] = 1.f - f;
        acc[mi][4 + j][e] = o;
      }

  // in-lane 4-step scan in TIME order (fw: mi 0->3, bw: mi 3->0), in place:
  // acc[mi][j] <- H_step(mi), acc[mi][2+j] <- P_step(mi)   (static indices only)
#define SCAN_STEP(MI) { f32x4 a_ = acc[MI][2 + j], c_ = acc[MI][j]; \
    Hc = a_ * Hc + c_; Pc = a_ * Pc; acc[MI][j] = Hc; acc[MI][2 + j] = Pc; }
  if (!dir) {
#pragma unroll
    for (int j = 0; j < 2; j++) {
      f32x4 Hc = {0.f, 0.f, 0.f, 0.f}, Pc = {1.f, 1.f, 1.f, 1.f};
      SCAN_STEP(0) SCAN_STEP(1) SCAN_STEP(2) SCAN_STEP(3)
    }
  } else {
#pragma unroll
    for (int j = 0; j < 2; j++) {
      f32x4 Hc = {0.f, 0.f, 0.f, 0.f}, Pc = {1.f, 1.f, 1.f, 1.f};
      SCAN_STEP(3) SCAN_STEP(2) SCAN_STEP(1) SCAN_STEP(0)
    }
  }
#undef SCAN_STEP

  // cross-wave combine: time-first half publishes its 4-step (P,H); the other
  // half prefixes with it.  fw: first = wm-half 0 (s_local 0..3); bw: wm-half 1.
  __syncthreads();                       // all K-loop LDS reads done -> reuse sA
  f32x4* ex = (f32x4*)sA;                // [2p][64 lanes][4] = 8 KB
  const int slot = p * 64 + lane;
  const bool firstHalf = ((wave >> 1) == (dir ? 1 : 0));
  if (firstHalf) {
#pragma unroll
    for (int j = 0; j < 2; j++) {
      f32x4 Pl = dir ? acc[0][2 + j] : acc[3][2 + j];
      f32x4 Hl = dir ? acc[0][j]     : acc[3][j];
      ex[slot * 4 + j * 2 + 0] = Pl;
      ex[slot * 4 + j * 2 + 1] = Hl;
    }
  }
  __syncthreads();
  if (!firstHalf) {
#pragma unroll
    for (int j = 0; j < 2; j++) {
      const f32x4 P0 = ex[slot * 4 + j * 2 + 0];
      const f32x4 H0 = ex[slot * 4 + j * 2 + 1];
#pragma unroll
      for (int mi = 0; mi < 4; mi++) {
        acc[mi][j]     = acc[mi][j] + acc[mi][2 + j] * H0;
        acc[mi][2 + j] = acc[mi][2 + j] * P0;
      }
    }
  }

  // u = o*H_prefix, v = o*P_prefix  -> fp16, dir-sliced buffers
  const size_t mrowbase = ((size_t)dir * MROWS + (size_t)(m0 + wm + lm)) * HID + hcol0;
#pragma unroll
  for (int mi = 0; mi < 4; mi++) {
    u16* Urow = U + mrowbase + (size_t)mi * 16 * HID;
    u16* Vrow = V + mrowbase + (size_t)mi * 16 * HID;
#pragma unroll
    for (int j = 0; j < 2; j++) {
      const f32x4 u = acc[mi][4 + j] * acc[mi][j];
      const f32x4 v = acc[mi][4 + j] * acc[mi][2 + j];
      uint2 up, vp;
      up.x = pkh(u[0], u[1]); up.y = pkh(u[2], u[3]);
      vp.x = pkh(v[0], v[1]); vp.y = pkh(v[2], v[3]);
      *(uint2*)(Urow + j * 16) = up;
      *(uint2*)(Vrow + j * 16) = vp;
    }
  }

  // chunk summary from the time-LAST half (full-chunk prefix after fixup)
  if (!firstHalf) {
    const int ct = dir ? (NCH - 1 - (int)blockIdx.y) : (int)blockIdx.y;
    float* ACc = ACn + (size_t)ct * (2 * NSEQ) + (size_t)(dir * 16 + lm) * 512 + hcol0;
#pragma unroll
    for (int j = 0; j < 2; j++) {
      const f32x4 Pf = dir ? acc[0][2 + j] : acc[3][2 + j];
      const f32x4 Hf = dir ? acc[0][j]     : acc[3][j];
      *(f32x4*)(ACc + j * 16)        = Pf;   // A_chunk
      *(f32x4*)(ACc + NSEQ + j * 16) = Hf;   // C_chunk
    }
  }
}

// ---- chunk combine: sequential over 256 chunks -> carry-in per chunk ----
__global__ void scan_combine(const float* __restrict__ ACn, float* __restrict__ Hin) {
  const int sidx = blockIdx.x * 256 + threadIdx.x;   // 16384 threads
  float carry = 0.f;
  for (int ct = 0; ct < NCH; ct++) {
    Hin[(size_t)ct * NSEQ + sidx] = carry;
    const float Aa = ACn[(size_t)ct * (2 * NSEQ) + sidx];
    const float Cc = ACn[(size_t)ct * (2 * NSEQ) + NSEQ + sidx];
    carry = fmaf(Aa, carry, Cc);
  }
}

// ---- output: out = u + v * h_in  (pure fma stream, no activations) ----
__global__ void scan_out(const u16* __restrict__ U, const u16* __restrict__ V,
                         const float* __restrict__ Hin, float* __restrict__ out) {
  const int tid = blockIdx.x * 256 + threadIdx.x;
  const int h   = (tid & 127) * 4;
  const int ct  = (tid >> 7) & 255;
  const int b   = (tid >> 15) & 15;
  const int dir = tid >> 19;
  const int sidx = (dir * BATCH + b) * HID + h;
  const float4 hv = *(const float4*)&Hin[(size_t)ct * NSEQ + sidx];
#pragma unroll
  for (int i = 0; i < 8; i++) {
    const int ts = ct * 8 + i;
    const int s  = dir ? (SEQ - 1 - ts) : ts;
    const size_t off = ((size_t)dir * MROWS + (size_t)s * BATCH + b) * HID + h;
    const uint2 uu = *(const uint2*)(U + off);
    const uint2 vv = *(const uint2*)(V + off);
    const float2 u01 = uph(uu.x), u23 = uph(uu.y);
    const float2 v01 = uph(vv.x), v23 = uph(vv.y);
    f32x4 ov;
    ov[0] = fmaf(v01.x, hv.x, u01.x);
    ov[1] = fmaf(v01.y, hv.y, u01.y);
    ov[2] = fmaf(v23.x, hv.z, u23.x);
    ov[3] = fmaf(v23.y, hv.w, u23.y);
    __builtin_nontemporal_store(ov,
        (f32x4*)&out[((size_t)s * BATCH + b) * (2 * HID) + (size_t)dir * HID + h]);
  }
}

extern "C" void kernel_launch(void* const* d_in, const int* in_sizes, int n_in,
                              void* d_out, int out_size, void* d_ws, size_t ws_size,
                              hipStream_t stream) {
  const float* X   = (const float*)d_in[0];
  const float* Wfw = (const float*)d_in[1];
  const float* bfw = (const float*)d_in[2];
  const float* Wbw = (const float*)d_in[3];
  const float* bbw = (const float*)d_in[4];
  float* out = (float*)d_out;

  char* ws = (char*)d_ws;
  const size_t XB  = (size_t)MROWS * KDIM * 2;          // 32 MiB
  const size_t WB  = (size_t)2 * 3 * HID * KDIM * 2;    // 3 MiB
  const size_t UVB = (size_t)2 * MROWS * HID * 2;       // 64 MiB each (2 dirs)
  u16*   Xb  = (u16*)ws;
  u16*   Wb  = (u16*)(ws + XB);
  u16*   U   = (u16*)(ws + XB + WB);
  u16*   V   = (u16*)(ws + XB + WB + UVB);
  float* ACn = (float*)(ws + XB + WB + 2 * UVB);        // 32 MiB
  float* Hin = ACn + (size_t)NCH * 2 * NSEQ;            // 16 MiB

  // bf16 conversions
  cvt_kernel<<<(MROWS * KDIM / 4) / 256, 256, 0, stream>>>(X, Xb, MROWS * KDIM / 4);
  cvt_kernel<<<(3 * HID * KDIM / 4) / 256, 256, 0, stream>>>(Wfw, Wb, 3 * HID * KDIM / 4);
  cvt_kernel<<<(3 * HID * KDIM / 4) / 256, 256, 0, stream>>>(Wbw, Wb + (size_t)3 * HID * KDIM,
                                                             3 * HID * KDIM / 4);

  // fused gates GEMM + intra-chunk scan: grid 16 (8 h-tiles x 2 dirs) x 256 m-tiles
  dim3 gg(16, 256);
  gemm_fused<<<gg, 256, 0, stream>>>(Xb, Wb, bfw, bbw, U, V, ACn);

  // chunk carry combine (256 chunks, 16384 sequences)
  scan_combine<<<NSEQ / 256, 256, 0, stream>>>(ACn, Hin);

  // output pass
  scan_out<<<(2 * BATCH * NCH * 128) / 256, 256, 0, stream>>>(U, V, Hin, out);
}

// Round 3
// 407.924 us; speedup vs baseline: 1.2169x; 1.2169x over previous
//
#include <hip/hip_runtime.h>
#include <hip/hip_bf16.h>
#include <hip/hip_fp16.h>

// Problem dims
#define SEQ   2048
#define BATCH 16
#define DIN   512
#define HID   512
#define MROWS (SEQ*BATCH)   // 32768 GEMM rows (s,b)
#define KDIM  DIN           // 512

// Chunking: one 128-row m-tile = 8 timesteps x 16 batches = one scan chunk
#define NCH  256            // chunks along S (SEQ/8)
#define NSEQ (2*BATCH*HID)  // 16384 independent recurrences

typedef unsigned short u16;
typedef __bf16 bf16x8 __attribute__((ext_vector_type(8)));
typedef float  f32x4  __attribute__((ext_vector_type(4)));

__device__ __forceinline__ u16 f2bf(float x) {
  unsigned u = __float_as_uint(x);
  unsigned r = (u + 0x7fffu + ((u >> 16) & 1u)) >> 16;   // RNE
  return (u16)r;
}

__device__ __forceinline__ unsigned pkh(float a, float b) {
  __half2 h = __floats2half2_rn(a, b);
  return *(const unsigned*)&h;
}
__device__ __forceinline__ float2 uph(unsigned x) {
  __half2 h = *(const __half2*)&x;
  return __half22float2(h);
}

__device__ __forceinline__ void async_ld16(const void* g, void* l) {
  __builtin_amdgcn_global_load_lds(
      (const __attribute__((address_space(1))) void*)g,
      (__attribute__((address_space(3))) void*)l, 16, 0, 0);
}

__device__ __forceinline__ float sig_fast(float x) {
  return __builtin_amdgcn_rcpf(1.f + __expf(-x));
}
__device__ __forceinline__ float tanh_fast(float x) {
  return 1.f - 2.f * __builtin_amdgcn_rcpf(1.f + __expf(2.f * x));
}

// ---- fp32 -> bf16 conversion (vectorized, 4 elems/thread) ----
__global__ void cvt_kernel(const float* __restrict__ in, u16* __restrict__ out, int n4) {
  int i = blockIdx.x * blockDim.x + threadIdx.x;
  if (i >= n4) return;
  const float4 v = ((const float4*)in)[i];
  uint2 r;
  r.x = (unsigned)f2bf(v.x) | ((unsigned)f2bf(v.y) << 16);
  r.y = (unsigned)f2bf(v.z) | ((unsigned)f2bf(v.w) << 16);
  ((uint2*)out)[i] = r;
}

// ---- Fused GEMM + bias + activation + intra-chunk scan epilogue ----
// Block: 128 m-rows (8 s x 16 b) x 96 n-cols = all 3 gates for a 32-h tile of
// one direction.  n_local = p*48 + gate*16 + hs  ->  W row = gate*512 + hb + p*16 + hs.
// Wave (4 waves, 2m x 2p): 64 m x 48 n; frag ni = gate.  acc = 12 f32x4 (48 VGPR)
// to keep <=128 VGPR -> 4 blocks/CU (the round-0 occupancy envelope).
// Epilogue: per lane (b = lane&15) scan 4 in-lane steps (mi) + cross-wave LDS
// exchange -> per-step prefixes (H,P); writes u = o*H, v = o*P (fp16, dir-sliced)
// and the per-chunk (A=P_last, C=H_last) summary (fp32).
__launch_bounds__(256, 4)
__global__ void gemm_fused(const u16* __restrict__ A, const u16* __restrict__ B,
                           const float* __restrict__ bfw, const float* __restrict__ bbw,
                           u16* __restrict__ U, u16* __restrict__ V,
                           float* __restrict__ ACn)
{
  __shared__ __align__(16) u16 sA[128 * 64];   // 16 KB
  __shared__ __align__(16) u16 sB[96 * 64];    // 12 KB

  const int t    = threadIdx.x;
  const int wave = t >> 6;
  const int lane = t & 63;
  const int m0  = blockIdx.y * 128;
  const int dir = blockIdx.x >> 4;
  const int hb  = (blockIdx.x & 15) * 32;
  const int wm  = (wave >> 1) * 64;   // m half
  const int p   = wave & 1;           // n half (h-sub-tile of 16)
  const int wn  = p * 48;

  f32x4 acc[4][3] = {};

  // staging: lane -> (rloc = lane>>3, c = lane&7); global 16B chunk g = c ^ rloc
  const int rloc = lane >> 3;
  const int gch  = (lane & 7) ^ rloc;
  const u16* gA  = A + (size_t)(m0 + wave * 32 + rloc) * KDIM + gch * 8;
  const u16* WbD = B + (size_t)dir * (3 * HID * KDIM);
  unsigned gBo[3];
#pragma unroll
  for (int j = 0; j < 3; j++) {
    const int nl = wave * 24 + j * 8 + rloc;      // 0..95
    const int pp = nl >= 48 ? 1 : 0;
    const int r  = nl - pp * 48;
    const int wrow = (r >> 4) * HID + hb + pp * 16 + (r & 15);
    gBo[j] = (unsigned)(wrow * KDIM + gch * 8);
  }

  const int lm = lane & 15;            // fragment index (= batch b for A rows)
  const int q  = lane >> 4;            // k-quad / n-reg group
  const int xs = lm & 7;               // read-side swizzle = row&7

  for (int kt = 0; kt < KDIM; kt += 64) {
    __syncthreads();
#pragma unroll
    for (int j = 0; j < 4; j++)
      async_ld16(gA + kt + (size_t)(j * 8) * KDIM, sA + (wave * 32 + j * 8) * 64);
#pragma unroll
    for (int j = 0; j < 3; j++)
      async_ld16(WbD + gBo[j] + kt, sB + (wave * 24 + j * 8) * 64);
    __syncthreads();

#pragma unroll
    for (int s = 0; s < 2; s++) {
      const int cofs = ((s * 4 + q) ^ xs) * 8;
      bf16x8 af[4], bfr[3];
#pragma unroll
      for (int mi = 0; mi < 4; mi++)
        af[mi] = *(const bf16x8*)(sA + (wm + mi * 16 + lm) * 64 + cofs);
#pragma unroll
      for (int ni = 0; ni < 3; ni++)
        bfr[ni] = *(const bf16x8*)(sB + (wn + ni * 16 + lm) * 64 + cofs);
#pragma unroll
      for (int mi = 0; mi < 4; mi++)
#pragma unroll
        for (int ni = 0; ni < 3; ni++)  // swapped: D col=lane&15 (m), row=q*4+i (n)
          acc[mi][ni] = __builtin_amdgcn_mfma_f32_16x16x32_bf16(bfr[ni], af[mi], acc[mi][ni], 0, 0, 0);
    }
  }

  // ---- epilogue ----
  // lane holds: m = m0 + wm + mi*16 + lm  (b = lm, s_local = (wave>>1)*4 + mi)
  //             h = hb + p*16 + q*4 + e, gate = ni
  const float* bias = dir ? bbw : bfw;
  const int hcol0 = hb + p * 16 + q * 4;

  const float4 t0 = *(const float4*)(bias + 0 * HID + hcol0);
  const float4 t1 = *(const float4*)(bias + 1 * HID + hcol0);
  const float4 t2 = *(const float4*)(bias + 2 * HID + hcol0);
  f32x4 bz, bff, bo;
  bz[0] = t0.x; bz[1] = t0.y; bz[2] = t0.z; bz[3] = t0.w;
  bff[0] = t1.x; bff[1] = t1.y; bff[2] = t1.z; bff[3] = t1.w;
  bo[0] = t2.x; bo[1] = t2.y; bo[2] = t2.z; bo[3] = t2.w;

  // activations in place: acc[mi][0] = c = f*z ; acc[mi][1] = a = 1-f ; acc[mi][2] = o
#pragma unroll
  for (int mi = 0; mi < 4; mi++)
#pragma unroll
    for (int e = 0; e < 4; e++) {
      const float z = tanh_fast(acc[mi][0][e] + bz[e]);
      const float f = sig_fast(acc[mi][1][e] + bff[e]);
      const float o = sig_fast(acc[mi][2][e] + bo[e]);
      acc[mi][0][e] = f * z;
      acc[mi][1][e] = 1.f - f;
      acc[mi][2][e] = o;
    }

  // in-lane 4-step scan in TIME order (fw: mi 0->3, bw: mi 3->0), in place:
  // acc[mi][0] <- H_step(mi), acc[mi][1] <- P_step(mi)   (static indices only)
#define SCAN_STEP(MI) { const f32x4 a_ = acc[MI][1], c_ = acc[MI][0]; \
    Hc = a_ * Hc + c_; Pc = a_ * Pc; acc[MI][0] = Hc; acc[MI][1] = Pc; }
  {
    f32x4 Hc = {0.f, 0.f, 0.f, 0.f}, Pc = {1.f, 1.f, 1.f, 1.f};
    if (!dir) { SCAN_STEP(0) SCAN_STEP(1) SCAN_STEP(2) SCAN_STEP(3) }
    else      { SCAN_STEP(3) SCAN_STEP(2) SCAN_STEP(1) SCAN_STEP(0) }
  }
#undef SCAN_STEP

  // cross-wave combine: time-first half publishes its 4-step (P,H); the other
  // half prefixes with it.  fw: first = wm-half 0 (s_local 0..3); bw: wm-half 1.
  __syncthreads();                       // all K-loop LDS reads done -> reuse sA
  f32x4* ex = (f32x4*)sA;                // [2p][64 lanes][2] = 4 KB
  const int slot = p * 64 + lane;
  const bool firstHalf = ((wave >> 1) == (dir ? 1 : 0));
  if (firstHalf) {
    ex[slot * 2 + 0] = dir ? acc[0][1] : acc[3][1];   // P
    ex[slot * 2 + 1] = dir ? acc[0][0] : acc[3][0];   // H
  }
  __syncthreads();
  if (!firstHalf) {
    const f32x4 P0 = ex[slot * 2 + 0];
    const f32x4 H0 = ex[slot * 2 + 1];
#pragma unroll
    for (int mi = 0; mi < 4; mi++) {
      acc[mi][0] = acc[mi][0] + acc[mi][1] * H0;
      acc[mi][1] = acc[mi][1] * P0;
    }
  }

  // u = o*H_prefix, v = o*P_prefix  -> fp16, dir-sliced buffers
  const size_t mrowbase = ((size_t)dir * MROWS + (size_t)(m0 + wm + lm)) * HID + hcol0;
#pragma unroll
  for (int mi = 0; mi < 4; mi++) {
    const f32x4 u = acc[mi][2] * acc[mi][0];
    const f32x4 v = acc[mi][2] * acc[mi][1];
    uint2 up, vp;
    up.x = pkh(u[0], u[1]); up.y = pkh(u[2], u[3]);
    vp.x = pkh(v[0], v[1]); vp.y = pkh(v[2], v[3]);
    *(uint2*)(U + mrowbase + (size_t)mi * 16 * HID) = up;
    *(uint2*)(V + mrowbase + (size_t)mi * 16 * HID) = vp;
  }

  // chunk summary from the time-LAST half (full-chunk prefix after fixup)
  if (!firstHalf) {
    const int ct = dir ? (NCH - 1 - (int)blockIdx.y) : (int)blockIdx.y;
    float* ACc = ACn + (size_t)ct * (2 * NSEQ) + (size_t)(dir * 16 + lm) * 512 + hcol0;
    const f32x4 Pf = dir ? acc[0][1] : acc[3][1];
    const f32x4 Hf = dir ? acc[0][0] : acc[3][0];
    *(f32x4*)(ACc)        = Pf;   // A_chunk
    *(f32x4*)(ACc + NSEQ) = Hf;   // C_chunk
  }
}

// ---- chunk combine: sequential over 256 chunks -> carry-in per chunk ----
__global__ void scan_combine(const float* __restrict__ ACn, float* __restrict__ Hin) {
  const int sidx = blockIdx.x * 256 + threadIdx.x;   // 16384 threads
  float carry = 0.f;
  for (int ct = 0; ct < NCH; ct++) {
    Hin[(size_t)ct * NSEQ + sidx] = carry;
    const float Aa = ACn[(size_t)ct * (2 * NSEQ) + sidx];
    const float Cc = ACn[(size_t)ct * (2 * NSEQ) + NSEQ + sidx];
    carry = fmaf(Aa, carry, Cc);
  }
}

// ---- output: out = u + v * h_in  (pure fma stream, 8 h per thread) ----
__global__ void scan_out(const u16* __restrict__ U, const u16* __restrict__ V,
                         const float* __restrict__ Hin, float* __restrict__ out) {
  const int tid = blockIdx.x * 256 + threadIdx.x;    // 524288 total
  const int h   = (tid & 63) * 8;
  const int ct  = (tid >> 6) & 255;
  const int b   = (tid >> 14) & 15;
  const int dir = tid >> 18;
  const int sidx = (dir * BATCH + b) * HID + h;
  const float4 hv0 = *(const float4*)&Hin[(size_t)ct * NSEQ + sidx];
  const float4 hv1 = *(const float4*)&Hin[(size_t)ct * NSEQ + sidx + 4];
#pragma unroll
  for (int i = 0; i < 8; i++) {
    const int ts = ct * 8 + i;
    const int s  = dir ? (SEQ - 1 - ts) : ts;
    const size_t off = ((size_t)dir * MROWS + (size_t)s * BATCH + b) * HID + h;
    const uint4 uu = *(const uint4*)(U + off);
    const uint4 vv = *(const uint4*)(V + off);
    const float2 u0 = uph(uu.x), u1 = uph(uu.y), u2 = uph(uu.z), u3 = uph(uu.w);
    const float2 v0 = uph(vv.x), v1 = uph(vv.y), v2 = uph(vv.z), v3 = uph(vv.w);
    f32x4 o0, o1;
    o0[0] = fmaf(v0.x, hv0.x, u0.x);
    o0[1] = fmaf(v0.y, hv0.y, u0.y);
    o0[2] = fmaf(v1.x, hv0.z, u1.x);
    o0[3] = fmaf(v1.y, hv0.w, u1.y);
    o1[0] = fmaf(v2.x, hv1.x, u2.x);
    o1[1] = fmaf(v2.y, hv1.y, u2.y);
    o1[2] = fmaf(v3.x, hv1.z, u3.x);
    o1[3] = fmaf(v3.y, hv1.w, u3.y);
    float* ob = &out[((size_t)s * BATCH + b) * (2 * HID) + (size_t)dir * HID + h];
    __builtin_nontemporal_store(o0, (f32x4*)ob);
    __builtin_nontemporal_store(o1, (f32x4*)(ob + 4));
  }
}

extern "C" void kernel_launch(void* const* d_in, const int* in_sizes, int n_in,
                              void* d_out, int out_size, void* d_ws, size_t ws_size,
                              hipStream_t stream) {
  const float* X   = (const float*)d_in[0];
  const float* Wfw = (const float*)d_in[1];
  const float* bfw = (const float*)d_in[2];
  const float* Wbw = (const float*)d_in[3];
  const float* bbw = (const float*)d_in[4];
  float* out = (float*)d_out;

  char* ws = (char*)d_ws;
  const size_t XB  = (size_t)MROWS * KDIM * 2;          // 32 MiB
  const size_t WB  = (size_t)2 * 3 * HID * KDIM * 2;    // 3 MiB
  const size_t UVB = (size_t)2 * MROWS * HID * 2;       // 64 MiB each (2 dirs)
  u16*   Xb  = (u16*)ws;
  u16*   Wb  = (u16*)(ws + XB);
  u16*   U   = (u16*)(ws + XB + WB);
  u16*   V   = (u16*)(ws + XB + WB + UVB);
  float* ACn = (float*)(ws + XB + WB + 2 * UVB);        // 32 MiB
  float* Hin = ACn + (size_t)NCH * 2 * NSEQ;            // 16 MiB

  // bf16 conversions
  cvt_kernel<<<(MROWS * KDIM / 4) / 256, 256, 0, stream>>>(X, Xb, MROWS * KDIM / 4);
  cvt_kernel<<<(3 * HID * KDIM / 4) / 256, 256, 0, stream>>>(Wfw, Wb, 3 * HID * KDIM / 4);
  cvt_kernel<<<(3 * HID * KDIM / 4) / 256, 256, 0, stream>>>(Wbw, Wb + (size_t)3 * HID * KDIM,
                                                             3 * HID * KDIM / 4);

  // fused gates GEMM + intra-chunk scan: grid 32 (16 h-tiles x 2 dirs) x 256 m-tiles
  dim3 gg(32, 256);
  gemm_fused<<<gg, 256, 0, stream>>>(Xb, Wb, bfw, bbw, U, V, ACn);

  // chunk carry combine (256 chunks, 16384 sequences)
  scan_combine<<<NSEQ / 256, 256, 0, stream>>>(ACn, Hin);

  // output pass (8 h per thread)
  scan_out<<<(2 * BATCH * NCH * 64) / 256, 256, 0, stream>>>(U, V, Hin, out);
}